// Round 1
// baseline (4732.219 us; speedup 1.0000x reference)
//
#include <hip/hip_runtime.h>
#include <math.h>

#define NG   65536
#define MTOK 512
#define DIM  512
#define SCALE_ATT 0.125f
#define LN_EPS 1e-5f

// ---------------------------------------------------------------------------
// 4x4 outer-product FMA helper
// ---------------------------------------------------------------------------
__device__ __forceinline__ void fma44(float (&acc)[4][4], const float4& a, const float4& b) {
    acc[0][0] += a.x*b.x; acc[0][1] += a.x*b.y; acc[0][2] += a.x*b.z; acc[0][3] += a.x*b.w;
    acc[1][0] += a.y*b.x; acc[1][1] += a.y*b.y; acc[1][2] += a.y*b.z; acc[1][3] += a.y*b.w;
    acc[2][0] += a.z*b.x; acc[2][1] += a.z*b.y; acc[2][2] += a.z*b.z; acc[2][3] += a.z*b.w;
    acc[3][0] += a.w*b.x; acc[3][1] += a.w*b.y; acc[3][2] += a.w*b.z; acc[3][3] += a.w*b.w;
}

// ---------------------------------------------------------------------------
// C[i,j] = sum_k A[i,k]*B[j,k] (+ A2[i,k]*B2[j,k]) (+bias1[j]+bias2[j]) (+addend[i,j])
// 128x128 tile, 256 threads, 8x8 microtile as four 4x4 quadrants, k-step 8.
// ---------------------------------------------------------------------------
__global__ __launch_bounds__(256)
void gemm_bt128(const float* __restrict__ A,  const float* __restrict__ B,
                const float* __restrict__ A2, const float* __restrict__ B2,
                const float* __restrict__ bias1, const float* __restrict__ bias2,
                const float* __restrict__ addend,
                float* __restrict__ C,
                int K, int lda, int ldb, long ldc)
{
    __shared__ __align__(16) float As[8][132];
    __shared__ __align__(16) float Bs[8][132];
    const int tid = threadIdx.x;
    const int tx = tid & 15;         // j quad index
    const int ty = tid >> 4;         // i quad index
    const long i0 = (long)blockIdx.y * 128;
    const long j0 = (long)blockIdx.x * 128;
    const int lr = tid >> 1;         // 0..127 tile row for staging
    const int lk = (tid & 1) * 4;    // 0 or 4

    float acc[2][2][4][4] = {};

    for (int pair = 0; pair < 2; ++pair) {
        const float* Ap = pair ? A2 : A;
        const float* Bp = pair ? B2 : B;
        if (Ap == nullptr) break;
        for (int k0 = 0; k0 < K; k0 += 8) {
            float4 av = *(const float4*)&Ap[(i0 + lr) * (long)lda + k0 + lk];
            float4 bv = *(const float4*)&Bp[(j0 + lr) * (long)ldb + k0 + lk];
            __syncthreads();
            As[lk+0][lr] = av.x; As[lk+1][lr] = av.y; As[lk+2][lr] = av.z; As[lk+3][lr] = av.w;
            Bs[lk+0][lr] = bv.x; Bs[lk+1][lr] = bv.y; Bs[lk+2][lr] = bv.z; Bs[lk+3][lr] = bv.w;
            __syncthreads();
            #pragma unroll
            for (int kk = 0; kk < 8; ++kk) {
                float4 a0 = *(const float4*)&As[kk][ty*4];
                float4 a1 = *(const float4*)&As[kk][64 + ty*4];
                float4 b0 = *(const float4*)&Bs[kk][tx*4];
                float4 b1 = *(const float4*)&Bs[kk][64 + tx*4];
                fma44(acc[0][0], a0, b0); fma44(acc[0][1], a0, b1);
                fma44(acc[1][0], a1, b0); fma44(acc[1][1], a1, b1);
            }
        }
    }

    #pragma unroll
    for (int qi = 0; qi < 2; ++qi) {
        #pragma unroll
        for (int rr = 0; rr < 4; ++rr) {
            const long r = i0 + qi*64 + ty*4 + rr;
            #pragma unroll
            for (int qj = 0; qj < 2; ++qj) {
                const long c = j0 + qj*64 + tx*4;
                float4 v;
                v.x = acc[qi][qj][rr][0]; v.y = acc[qi][qj][rr][1];
                v.z = acc[qi][qj][rr][2]; v.w = acc[qi][qj][rr][3];
                if (bias1) { v.x += bias1[c]; v.y += bias1[c+1]; v.z += bias1[c+2]; v.w += bias1[c+3]; }
                if (bias2) { v.x += bias2[c]; v.y += bias2[c+1]; v.z += bias2[c+2]; v.w += bias2[c+3]; }
                if (addend) {
                    float4 ad = *(const float4*)&addend[r*ldc + c];
                    v.x += ad.x; v.y += ad.y; v.z += ad.z; v.w += ad.w;
                }
                *(float4*)&C[r*ldc + c] = v;
            }
        }
    }
}

// ---------------------------------------------------------------------------
// Split-K GEMM: Cpart[z][i,j] = sum_{k in chunk z} A[i,k]*B[k,j]
// ---------------------------------------------------------------------------
__global__ __launch_bounds__(256)
void gemm_ab128_splitk(const float* __restrict__ A, const float* __restrict__ B,
                       float* __restrict__ Cpart, int kchunk)
{
    __shared__ __align__(16) float As[8][132];
    __shared__ __align__(16) float Bs[8][132];
    const int tid = threadIdx.x;
    const int tx = tid & 15;
    const int ty = tid >> 4;
    const long i0 = (long)blockIdx.y * 128;
    const long j0 = (long)blockIdx.x * 128;
    const int kbase = blockIdx.z * kchunk;
    const int lr = tid >> 1;
    const int lk = (tid & 1) * 4;
    const int bkr = tid >> 5;        // 0..7  B k-row
    const int bc  = (tid & 31) * 4;  // 0..124

    float acc[2][2][4][4] = {};

    for (int k0 = kbase; k0 < kbase + kchunk; k0 += 8) {
        float4 av = *(const float4*)&A[(i0 + lr) * 65536L + k0 + lk];
        float4 bv = *(const float4*)&B[(long)(k0 + bkr) * 512 + j0 + bc];
        __syncthreads();
        As[lk+0][lr] = av.x; As[lk+1][lr] = av.y; As[lk+2][lr] = av.z; As[lk+3][lr] = av.w;
        *(float4*)&Bs[bkr][bc] = bv;
        __syncthreads();
        #pragma unroll
        for (int kk = 0; kk < 8; ++kk) {
            float4 a0 = *(const float4*)&As[kk][ty*4];
            float4 a1 = *(const float4*)&As[kk][64 + ty*4];
            float4 b0 = *(const float4*)&Bs[kk][tx*4];
            float4 b1 = *(const float4*)&Bs[kk][64 + tx*4];
            fma44(acc[0][0], a0, b0); fma44(acc[0][1], a0, b1);
            fma44(acc[1][0], a1, b0); fma44(acc[1][1], a1, b1);
        }
    }

    float* Cp = Cpart + (size_t)blockIdx.z * (512*512);
    #pragma unroll
    for (int qi = 0; qi < 2; ++qi) {
        #pragma unroll
        for (int rr = 0; rr < 4; ++rr) {
            const long r = i0 + qi*64 + ty*4 + rr;
            #pragma unroll
            for (int qj = 0; qj < 2; ++qj) {
                const long c = j0 + qj*64 + tx*4;
                float4 v;
                v.x = acc[qi][qj][rr][0]; v.y = acc[qi][qj][rr][1];
                v.z = acc[qi][qj][rr][2]; v.w = acc[qi][qj][rr][3];
                *(float4*)&Cp[r*512 + c] = v;
            }
        }
    }
}

__global__ __launch_bounds__(256)
void reduce_parts16(const float* __restrict__ part, float* __restrict__ outp)
{
    const size_t idx = ((size_t)blockIdx.x * 256 + threadIdx.x) * 4;
    float4 s = *(const float4*)&part[idx];
    #pragma unroll
    for (int p = 1; p < 16; ++p) {
        float4 v = *(const float4*)&part[(size_t)p * 262144 + idx];
        s.x += v.x; s.y += v.y; s.z += v.z; s.w += v.w;
    }
    *(float4*)&outp[idx] = s;
}

// ---------------------------------------------------------------------------
// In-place row softmax over 65536 columns; one block per row.
// ---------------------------------------------------------------------------
__global__ __launch_bounds__(256)
void softmax_rows(float* __restrict__ L)
{
    __shared__ float red[4];
    const long base = (long)blockIdx.x * 65536;
    const int tid = threadIdx.x;

    float mx = -3.0e38f;
    for (int i = tid*4; i < 65536; i += 1024) {
        float4 v = *(const float4*)&L[base + i];
        mx = fmaxf(mx, fmaxf(fmaxf(v.x, v.y), fmaxf(v.z, v.w)));
    }
    #pragma unroll
    for (int off = 32; off > 0; off >>= 1) mx = fmaxf(mx, __shfl_xor(mx, off, 64));
    if ((tid & 63) == 0) red[tid >> 6] = mx;
    __syncthreads();
    mx = fmaxf(fmaxf(red[0], red[1]), fmaxf(red[2], red[3]));
    __syncthreads();

    float s = 0.f;
    for (int i = tid*4; i < 65536; i += 1024) {
        float4 v = *(const float4*)&L[base + i];
        v.x = __expf(v.x - mx); v.y = __expf(v.y - mx);
        v.z = __expf(v.z - mx); v.w = __expf(v.w - mx);
        *(float4*)&L[base + i] = v;
        s += v.x + v.y + v.z + v.w;
    }
    #pragma unroll
    for (int off = 32; off > 0; off >>= 1) s += __shfl_xor(s, off, 64);
    if ((tid & 63) == 0) red[tid >> 6] = s;
    __syncthreads();
    s = red[0] + red[1] + red[2] + red[3];
    const float inv = 1.f / s;

    for (int i = tid*4; i < 65536; i += 1024) {
        float4 v = *(const float4*)&L[base + i];
        v.x *= inv; v.y *= inv; v.z *= inv; v.w *= inv;
        *(float4*)&L[base + i] = v;
    }
}

// ---------------------------------------------------------------------------
// Ktr[d][m] = K[m][d] * SCALE_ATT   (512x512, pre-scaled transposed K)
// ---------------------------------------------------------------------------
__global__ __launch_bounds__(256)
void transpose_scale512(const float* __restrict__ in, float* __restrict__ outp)
{
    __shared__ float t[32][33];
    const int lx = threadIdx.x & 31;
    const int ly = threadIdx.x >> 5;       // 0..7
    const int m0 = blockIdx.y * 32;
    const int d0 = blockIdx.x * 32;
    #pragma unroll
    for (int i = 0; i < 32; i += 8)
        t[ly + i][lx] = in[(long)(m0 + ly + i) * 512 + d0 + lx] * SCALE_ATT;
    __syncthreads();
    #pragma unroll
    for (int i = 0; i < 32; i += 8)
        outp[(long)(d0 + ly + i) * 512 + m0 + lx] = t[lx][ly + i];
}

// ---------------------------------------------------------------------------
// Fused attention + residual + LayerNorm, register-tiled to be VALU-bound.
//
// 32 Q-rows/block, 256 threads = 4 waves. Wave w owns rows w*8..w*8+7; lane l
// owns output cols {4l..4l+3} and {256+4l..256+4l+3}. Scores (then P, then O)
// live in registers, 64 floats/thread. Softmax = register + shfl_xor (rows
// never cross waves). A-operand (Q / P) read straight from global (wave-
// uniform address -> single L1 line broadcast, zero LDS traffic). P is staged
// through d_out itself (each block only touches its own 32 rows, and Q rows
// are dead once phase 1 completes). LDS holds only K^T / V tiles: linear
// [16][512] double-buffered (2 x 32KB), all LDS accesses are contiguous
// float4 per lane -> conflict-free; next tile prefetched to registers during
// compute, written after, one barrier per chunk.
// Inner step: 64 FMAs per 2 ds_read_b128  (vs 4 FMAs per b32+b128 before).
// ---------------------------------------------------------------------------
__global__ __launch_bounds__(256)
void attn_ln2(const float* Qm, const float* __restrict__ Ktr,
              const float* __restrict__ Vm, const float* __restrict__ gres,
              const float* __restrict__ gamma, const float* __restrict__ beta,
              float* Pm, float* outp)
{
    __shared__ __align__(16) float Bt[2][16*512];   // 64 KiB total
    const int tid = threadIdx.x;
    const int w   = tid >> 6;          // wave 0..3
    const int l   = tid & 63;          // lane
    const long n0 = (long)blockIdx.x * 32;
    const int r0  = w * 8;             // wave's first block-local row
    const int c0  = l * 4;             // lane's first col (second group at +256)

    const float* Qb = Qm + (n0 + r0) * DIM;

    float s[8][8];
    #pragma unroll
    for (int i = 0; i < 8; ++i)
        #pragma unroll
        for (int j = 0; j < 8; ++j) s[i][j] = 0.f;

    // ================= phase 1: S = Q @ Ktr (Ktr pre-scaled) =================
    {
        #pragma unroll
        for (int j = 0; j < 8; ++j) {
            float4 v = *(const float4*)(Ktr + (j*256 + tid)*4);
            *(float4*)&Bt[0][(j*256 + tid)*4] = v;
        }
        __syncthreads();

        for (int ck = 0; ck < 32; ++ck) {
            const int cur = ck & 1;
            float4 pf[8];
            if (ck < 31) {
                const float* src = Ktr + (ck + 1) * 8192;
                #pragma unroll
                for (int j = 0; j < 8; ++j) pf[j] = *(const float4*)(src + (j*256 + tid)*4);
            }
            const float* Bp = &Bt[cur][0];
            const float* Qc = Qb + ck * 16;
            #pragma unroll
            for (int d4 = 0; d4 < 4; ++d4) {
                float qa[8][4];
                #pragma unroll
                for (int i = 0; i < 8; ++i) {
                    float4 t = *(const float4*)(Qc + i*DIM + d4*4);
                    qa[i][0] = t.x; qa[i][1] = t.y; qa[i][2] = t.z; qa[i][3] = t.w;
                }
                #pragma unroll
                for (int dd = 0; dd < 4; ++dd) {
                    const float* br = Bp + (d4*4 + dd) * 512;
                    float4 b0 = *(const float4*)(br + c0);
                    float4 b1 = *(const float4*)(br + 256 + c0);
                    #pragma unroll
                    for (int i = 0; i < 8; ++i) {
                        const float ai = qa[i][dd];
                        s[i][0] += ai*b0.x; s[i][1] += ai*b0.y;
                        s[i][2] += ai*b0.z; s[i][3] += ai*b0.w;
                        s[i][4] += ai*b1.x; s[i][5] += ai*b1.y;
                        s[i][6] += ai*b1.z; s[i][7] += ai*b1.w;
                    }
                }
            }
            if (ck < 31) {
                #pragma unroll
                for (int j = 0; j < 8; ++j)
                    *(float4*)&Bt[cur ^ 1][(j*256 + tid)*4] = pf[j];
            }
            __syncthreads();
        }
    }

    // ======== phase 2: softmax in registers, store P rows to scratch ========
    float* Pb = Pm + (n0 + r0) * DIM;
    #pragma unroll
    for (int i = 0; i < 8; ++i) {
        float mx = s[i][0];
        #pragma unroll
        for (int j = 1; j < 8; ++j) mx = fmaxf(mx, s[i][j]);
        #pragma unroll
        for (int off = 32; off > 0; off >>= 1) mx = fmaxf(mx, __shfl_xor(mx, off, 64));
        float sum = 0.f;
        #pragma unroll
        for (int j = 0; j < 8; ++j) { s[i][j] = __expf(s[i][j] - mx); sum += s[i][j]; }
        #pragma unroll
        for (int off = 32; off > 0; off >>= 1) sum += __shfl_xor(sum, off, 64);
        const float inv = 1.f / sum;
        float4 p0, p1;
        p0.x = s[i][0]*inv; p0.y = s[i][1]*inv; p0.z = s[i][2]*inv; p0.w = s[i][3]*inv;
        p1.x = s[i][4]*inv; p1.y = s[i][5]*inv; p1.z = s[i][6]*inv; p1.w = s[i][7]*inv;
        *(float4*)&Pb[i*DIM + c0]       = p0;
        *(float4*)&Pb[i*DIM + 256 + c0] = p1;
    }

    // ================= phase 3: O = P @ V =================
    float o[8][8];
    #pragma unroll
    for (int i = 0; i < 8; ++i)
        #pragma unroll
        for (int j = 0; j < 8; ++j) o[i][j] = 0.f;

    {
        #pragma unroll
        for (int j = 0; j < 8; ++j) {
            float4 v = *(const float4*)(Vm + (j*256 + tid)*4);
            *(float4*)&Bt[0][(j*256 + tid)*4] = v;
        }
        __syncthreads();   // also drains P stores (vmcnt) before any P load

        for (int ck = 0; ck < 32; ++ck) {
            const int cur = ck & 1;
            float4 pf[8];
            if (ck < 31) {
                const float* src = Vm + (ck + 1) * 8192;
                #pragma unroll
                for (int j = 0; j < 8; ++j) pf[j] = *(const float4*)(src + (j*256 + tid)*4);
            }
            const float* Bp = &Bt[cur][0];
            const float* Pc = Pb + ck * 16;
            #pragma unroll
            for (int d4 = 0; d4 < 4; ++d4) {
                float qa[8][4];
                #pragma unroll
                for (int i = 0; i < 8; ++i) {
                    float4 t = *(const float4*)(Pc + i*DIM + d4*4);
                    qa[i][0] = t.x; qa[i][1] = t.y; qa[i][2] = t.z; qa[i][3] = t.w;
                }
                #pragma unroll
                for (int dd = 0; dd < 4; ++dd) {
                    const float* br = Bp + (d4*4 + dd) * 512;
                    float4 b0 = *(const float4*)(br + c0);
                    float4 b1 = *(const float4*)(br + 256 + c0);
                    #pragma unroll
                    for (int i = 0; i < 8; ++i) {
                        const float ai = qa[i][dd];
                        o[i][0] += ai*b0.x; o[i][1] += ai*b0.y;
                        o[i][2] += ai*b0.z; o[i][3] += ai*b0.w;
                        o[i][4] += ai*b1.x; o[i][5] += ai*b1.y;
                        o[i][6] += ai*b1.z; o[i][7] += ai*b1.w;
                    }
                }
            }
            if (ck < 31) {
                #pragma unroll
                for (int j = 0; j < 8; ++j)
                    *(float4*)&Bt[cur ^ 1][(j*256 + tid)*4] = pf[j];
            }
            __syncthreads();
        }
    }

    // ================= phase 4: += g, LayerNorm, store out =================
    const float* gb = gres + (n0 + r0) * DIM;
    const float4 gm0 = *(const float4*)(gamma + c0);
    const float4 gm1 = *(const float4*)(gamma + 256 + c0);
    const float4 bt0 = *(const float4*)(beta + c0);
    const float4 bt1 = *(const float4*)(beta + 256 + c0);
    #pragma unroll
    for (int i = 0; i < 8; ++i) {
        float4 g0 = *(const float4*)(gb + i*DIM + c0);
        float4 g1 = *(const float4*)(gb + i*DIM + 256 + c0);
        o[i][0] += g0.x; o[i][1] += g0.y; o[i][2] += g0.z; o[i][3] += g0.w;
        o[i][4] += g1.x; o[i][5] += g1.y; o[i][6] += g1.z; o[i][7] += g1.w;

        float sum = 0.f;
        #pragma unroll
        for (int j = 0; j < 8; ++j) sum += o[i][j];
        #pragma unroll
        for (int off = 32; off > 0; off >>= 1) sum += __shfl_xor(sum, off, 64);
        const float mu = sum * (1.f/512.f);

        float qs = 0.f;
        #pragma unroll
        for (int j = 0; j < 8; ++j) { float d = o[i][j] - mu; qs += d*d; }
        #pragma unroll
        for (int off = 32; off > 0; off >>= 1) qs += __shfl_xor(qs, off, 64);
        const float rstd = rsqrtf(qs * (1.f/512.f) + LN_EPS);

        float4 o0, o1;
        o0.x = (o[i][0]-mu)*rstd*gm0.x + bt0.x;
        o0.y = (o[i][1]-mu)*rstd*gm0.y + bt0.y;
        o0.z = (o[i][2]-mu)*rstd*gm0.z + bt0.z;
        o0.w = (o[i][3]-mu)*rstd*gm0.w + bt0.w;
        o1.x = (o[i][4]-mu)*rstd*gm1.x + bt1.x;
        o1.y = (o[i][5]-mu)*rstd*gm1.y + bt1.y;
        o1.z = (o[i][6]-mu)*rstd*gm1.z + bt1.z;
        o1.w = (o[i][7]-mu)*rstd*gm1.w + bt1.w;
        *(float4*)&outp[(n0 + r0 + i)*DIM + c0]       = o0;
        *(float4*)&outp[(n0 + r0 + i)*DIM + 256 + c0] = o1;
    }
}

// ---------------------------------------------------------------------------
extern "C" void kernel_launch(void* const* d_in, const int* in_sizes, int n_in,
                              void* d_out, int out_size, void* d_ws, size_t ws_size,
                              hipStream_t stream)
{
    (void)in_sizes; (void)n_in; (void)out_size; (void)ws_size;
    const float* g    = (const float*)d_in[0];
    const float* g_p  = (const float*)d_in[1];
    const float* W    = (const float*)d_in[2];   // [1, 512, 512] == Ws
    const float* Wq   = (const float*)d_in[3];
    const float* bq   = (const float*)d_in[4];
    const float* Wk   = (const float*)d_in[5];
    const float* bk   = (const float*)d_in[6];
    const float* Wv   = (const float*)d_in[7];
    const float* bv   = (const float*)d_in[8];
    const float* Wgp  = (const float*)d_in[9];
    const float* bgp  = (const float*)d_in[10];
    const float* Wkp  = (const float*)d_in[11];
    const float* bkp  = (const float*)d_in[12];
    const float* gamma= (const float*)d_in[13];
    const float* beta = (const float*)d_in[14];
    float* out = (float*)d_out;

    // workspace: 16 split-K partials (16 MB) + k_p0 + k_p + K + V  (= 20 MB)
    float* w    = (float*)d_ws;
    float* part = w;
    float* kp0  = w + (size_t)16*262144;
    float* kp   = kp0 + 262144;
    float* Kmat = kp  + 262144;
    float* Vmat = Kmat + 262144;
    float* Ktr  = part;   // reuse split-K scratch (dead after reduce_parts16)

    // 1) L = Ws @ g^T  -> d_out viewed as [512, 65536]
    gemm_bt128<<<dim3(512, 4), 256, 0, stream>>>(
        W, g, nullptr, nullptr, nullptr, nullptr, nullptr,
        out, 512, 512, 512, (long)65536);

    // 2) pool = softmax(L) rows, in place
    softmax_rows<<<dim3(512), 256, 0, stream>>>(out);

    // 3) k_p0 = pool @ g_p  (split-K 16)
    gemm_ab128_splitk<<<dim3(4, 4, 16), 256, 0, stream>>>(out, g_p, part, 4096);
    reduce_parts16<<<dim3(256), 256, 0, stream>>>(part, kp0);

    // 4) small GEMMs: k_p, K, V
    gemm_bt128<<<dim3(4, 4), 256, 0, stream>>>(
        kp0, Wkp, nullptr, nullptr, bkp, nullptr, nullptr, kp, 512, 512, 512, (long)512);
    gemm_bt128<<<dim3(4, 4), 256, 0, stream>>>(
        W, Wk, nullptr, nullptr, bk, nullptr, kp, Kmat, 512, 512, 512, (long)512);
    gemm_bt128<<<dim3(4, 4), 256, 0, stream>>>(
        W, Wv, nullptr, nullptr, bv, nullptr, nullptr, Vmat, 512, 512, 512, (long)512);

    // 4b) Ktr = Kmat^T * SCALE (into dead split-K scratch)
    transpose_scale512<<<dim3(16, 16), 256, 0, stream>>>(Kmat, Ktr);

    // 5) Q = g @ Wq^T + g_p @ Wgp^T + bq + bgp  -> d_out as [65536, 512]
    gemm_bt128<<<dim3(4, 512), 256, 0, stream>>>(
        g, Wq, g_p, Wgp, bq, bgp, nullptr, out, 512, 512, 512, (long)512);

    // 6) fused attention + residual + LayerNorm (Q / P-scratch / out all = d_out)
    attn_ln2<<<dim3(2048), 256, 0, stream>>>(out, Ktr, Vmat, g, gamma, beta, out, out);
}

// Round 2
// 2478.131 us; speedup vs baseline: 1.9096x; 1.9096x over previous
//
#include <hip/hip_runtime.h>
#include <math.h>

#define NG   65536
#define MTOK 512
#define DIM  512
#define SCALE_ATT 0.125f
#define LN_EPS 1e-5f

typedef __attribute__((ext_vector_type(8))) short bf16x8;
typedef __attribute__((ext_vector_type(4))) float f32x4;

// round-to-nearest-even fp32 -> bf16 (bits)
__device__ __forceinline__ ushort f2bf_rn(float f) {
    unsigned u = __float_as_uint(f);
    u += 0x7FFFu + ((u >> 16) & 1u);
    return (ushort)(u >> 16);
}
__device__ __forceinline__ float bf2f(ushort h) {
    return __uint_as_float(((unsigned)h) << 16);
}

// ---------------------------------------------------------------------------
// 4x4 outer-product FMA helper (fp32 path, small GEMMs)
// ---------------------------------------------------------------------------
__device__ __forceinline__ void fma44(float (&acc)[4][4], const float4& a, const float4& b) {
    acc[0][0] += a.x*b.x; acc[0][1] += a.x*b.y; acc[0][2] += a.x*b.z; acc[0][3] += a.x*b.w;
    acc[1][0] += a.y*b.x; acc[1][1] += a.y*b.y; acc[1][2] += a.y*b.z; acc[1][3] += a.y*b.w;
    acc[2][0] += a.z*b.x; acc[2][1] += a.z*b.y; acc[2][2] += a.z*b.z; acc[2][3] += a.z*b.w;
    acc[3][0] += a.w*b.x; acc[3][1] += a.w*b.y; acc[3][2] += a.w*b.z; acc[3][3] += a.w*b.w;
}

// ---------------------------------------------------------------------------
// fp32 bt GEMM (kept for the small 512^3 GEMMs)
// C[i,j] = sum_k A[i,k]*B[j,k] (+pairs)(+biases)(+addend), *cscale on acc
// ---------------------------------------------------------------------------
__global__ __launch_bounds__(256)
void gemm_bt128(const float* __restrict__ A,  const float* __restrict__ B,
                const float* __restrict__ A2, const float* __restrict__ B2,
                const float* __restrict__ bias1, const float* __restrict__ bias2,
                const float* __restrict__ addend,
                float* __restrict__ C,
                int K, int lda, int ldb, long ldc, float cscale)
{
    __shared__ __align__(16) float As[8][132];
    __shared__ __align__(16) float Bs[8][132];
    const int tid = threadIdx.x;
    const int tx = tid & 15;
    const int ty = tid >> 4;
    const long i0 = (long)blockIdx.y * 128;
    const long j0 = (long)blockIdx.x * 128;
    const int lr = tid >> 1;
    const int lk = (tid & 1) * 4;

    float acc[2][2][4][4] = {};

    for (int pair = 0; pair < 2; ++pair) {
        const float* Ap = pair ? A2 : A;
        const float* Bp = pair ? B2 : B;
        if (Ap == nullptr) break;
        for (int k0 = 0; k0 < K; k0 += 8) {
            float4 av = *(const float4*)&Ap[(i0 + lr) * (long)lda + k0 + lk];
            float4 bv = *(const float4*)&Bp[(j0 + lr) * (long)ldb + k0 + lk];
            __syncthreads();
            As[lk+0][lr] = av.x; As[lk+1][lr] = av.y; As[lk+2][lr] = av.z; As[lk+3][lr] = av.w;
            Bs[lk+0][lr] = bv.x; Bs[lk+1][lr] = bv.y; Bs[lk+2][lr] = bv.z; Bs[lk+3][lr] = bv.w;
            __syncthreads();
            #pragma unroll
            for (int kk = 0; kk < 8; ++kk) {
                float4 a0 = *(const float4*)&As[kk][ty*4];
                float4 a1 = *(const float4*)&As[kk][64 + ty*4];
                float4 b0 = *(const float4*)&Bs[kk][tx*4];
                float4 b1 = *(const float4*)&Bs[kk][64 + tx*4];
                fma44(acc[0][0], a0, b0); fma44(acc[0][1], a0, b1);
                fma44(acc[1][0], a1, b0); fma44(acc[1][1], a1, b1);
            }
        }
    }

    #pragma unroll
    for (int qi = 0; qi < 2; ++qi) {
        #pragma unroll
        for (int rr = 0; rr < 4; ++rr) {
            const long r = i0 + qi*64 + ty*4 + rr;
            #pragma unroll
            for (int qj = 0; qj < 2; ++qj) {
                const long c = j0 + qj*64 + tx*4;
                float4 v;
                v.x = acc[qi][qj][rr][0]*cscale; v.y = acc[qi][qj][rr][1]*cscale;
                v.z = acc[qi][qj][rr][2]*cscale; v.w = acc[qi][qj][rr][3]*cscale;
                if (bias1) { v.x += bias1[c]; v.y += bias1[c+1]; v.z += bias1[c+2]; v.w += bias1[c+3]; }
                if (bias2) { v.x += bias2[c]; v.y += bias2[c+1]; v.z += bias2[c+2]; v.w += bias2[c+3]; }
                if (addend) {
                    float4 ad = *(const float4*)&addend[r*ldc + c];
                    v.x += ad.x; v.y += ad.y; v.z += ad.z; v.w += ad.w;
                }
                *(float4*)&C[r*ldc + c] = v;
            }
        }
    }
}

// ---------------------------------------------------------------------------
// MFMA split-bf16 bt GEMM: C[i,j] = sum_k A[i,k]*B[j,k] (+pair2)(+biases)
// (+addend), acc*cscale. Inputs fp32, converted on the fly to hi/lo bf16
// (3-product split => ~fp32 precision at MFMA rate).
// 128x128 tile, BK=32, 256 thr = 4 waves (2x2), wave tile 64x64 = 4x4 frags
// of v_mfma_f32_16x16x32_bf16. LDS: 4 planes [4 kc][128 row][8 k] bf16 with
// XOR cell swizzle (cell = row&~7 | (row^kc)&7) -> conflict-free b128 reads
// and conflict-free staging writes. 32 KiB LDS total (>=2 blocks/CU).
// Requires M,N mult of 128, K mult of 32. Global ptrs 16B-aligned rows.
// ---------------------------------------------------------------------------
__global__ __launch_bounds__(256)
void mfma_bt(const float* __restrict__ A,  const float* __restrict__ B,
             const float* __restrict__ A2, const float* __restrict__ B2,
             const float* __restrict__ bias1, const float* __restrict__ bias2,
             const float* __restrict__ addend,
             float* __restrict__ C,
             int K, int lda, int ldb, long ldc, float cscale)
{
    __shared__ __align__(16) ushort Ah[4096];
    __shared__ __align__(16) ushort Al[4096];
    __shared__ __align__(16) ushort Bh[4096];
    __shared__ __align__(16) ushort Bl[4096];

    const int t  = threadIdx.x;
    const int ln = t & 63;
    const int wv = t >> 6;
    const int G  = ln >> 4;          // k-chunk group 0..3
    const int rr = ln & 15;          // frag row/col lane
    const int wr = (wv >> 1) * 64;   // wave row offset in tile
    const int wc = (wv & 1) * 64;    // wave col offset in tile
    const long i0 = (long)blockIdx.y * 128;
    const long j0 = (long)blockIdx.x * 128;

    // staging map: 4 float4 per matrix per K32 step
    int srow[4], skq[4], sus[4];
    #pragma unroll
    for (int it = 0; it < 4; ++it) {
        int flat4 = it*256 + t;
        int row = flat4 >> 3;            // 0..127
        int k4  = (flat4 & 7) * 4;       // 0..28
        int kc  = k4 >> 3;               // 0..3
        int ko  = k4 & 7;                // 0 or 4
        int cell = (row & ~7) | ((row ^ kc) & 7);
        srow[it] = row; skq[it] = k4; sus[it] = kc*1024 + cell*8 + ko;
    }

    f32x4 acc[4][4];
    #pragma unroll
    for (int a = 0; a < 4; ++a)
        #pragma unroll
        for (int b = 0; b < 4; ++b) acc[a][b] = (f32x4){0.f, 0.f, 0.f, 0.f};

    for (int pair = 0; pair < 2; ++pair) {
        const float* Ap = pair ? A2 : A;
        const float* Bp = pair ? B2 : B;
        if (Ap == nullptr) break;

        float4 pa[4], pb[4];
        #pragma unroll
        for (int it = 0; it < 4; ++it) {
            pa[it] = *(const float4*)&Ap[(i0 + srow[it]) * (long)lda + skq[it]];
            pb[it] = *(const float4*)&Bp[(j0 + srow[it]) * (long)ldb + skq[it]];
        }

        for (int k0 = 0; k0 < K; k0 += 32) {
            __syncthreads();   // prior compute done reading LDS
            #pragma unroll
            for (int it = 0; it < 4; ++it) {
                ushort4 h, l;
                h.x = f2bf_rn(pa[it].x); l.x = f2bf_rn(pa[it].x - bf2f(h.x));
                h.y = f2bf_rn(pa[it].y); l.y = f2bf_rn(pa[it].y - bf2f(h.y));
                h.z = f2bf_rn(pa[it].z); l.z = f2bf_rn(pa[it].z - bf2f(h.z));
                h.w = f2bf_rn(pa[it].w); l.w = f2bf_rn(pa[it].w - bf2f(h.w));
                *(ushort4*)&Ah[sus[it]] = h;
                *(ushort4*)&Al[sus[it]] = l;
                h.x = f2bf_rn(pb[it].x); l.x = f2bf_rn(pb[it].x - bf2f(h.x));
                h.y = f2bf_rn(pb[it].y); l.y = f2bf_rn(pb[it].y - bf2f(h.y));
                h.z = f2bf_rn(pb[it].z); l.z = f2bf_rn(pb[it].z - bf2f(h.z));
                h.w = f2bf_rn(pb[it].w); l.w = f2bf_rn(pb[it].w - bf2f(h.w));
                *(ushort4*)&Bh[sus[it]] = h;
                *(ushort4*)&Bl[sus[it]] = l;
            }
            __syncthreads();

            if (k0 + 32 < K) {   // prefetch next chunk while computing
                #pragma unroll
                for (int it = 0; it < 4; ++it) {
                    pa[it] = *(const float4*)&Ap[(i0 + srow[it]) * (long)lda + k0 + 32 + skq[it]];
                    pb[it] = *(const float4*)&Bp[(j0 + srow[it]) * (long)ldb + k0 + 32 + skq[it]];
                }
            }

            bf16x8 ahr[4], alr[4];
            #pragma unroll
            for (int mf = 0; mf < 4; ++mf) {
                int row = wr + mf*16 + rr;
                int cell = (row & ~7) | ((row ^ G) & 7);
                int us = G*1024 + cell*8;
                ahr[mf] = *(bf16x8*)&Ah[us];
                alr[mf] = *(bf16x8*)&Al[us];
            }
            #pragma unroll
            for (int nf = 0; nf < 4; ++nf) {
                int row = wc + nf*16 + rr;
                int cell = (row & ~7) | ((row ^ G) & 7);
                int us = G*1024 + cell*8;
                bf16x8 bh = *(bf16x8*)&Bh[us];
                bf16x8 bl = *(bf16x8*)&Bl[us];
                #pragma unroll
                for (int mf = 0; mf < 4; ++mf) {
                    acc[mf][nf] = __builtin_amdgcn_mfma_f32_16x16x32_bf16(ahr[mf], bh, acc[mf][nf], 0, 0, 0);
                    acc[mf][nf] = __builtin_amdgcn_mfma_f32_16x16x32_bf16(ahr[mf], bl, acc[mf][nf], 0, 0, 0);
                    acc[mf][nf] = __builtin_amdgcn_mfma_f32_16x16x32_bf16(alr[mf], bh, acc[mf][nf], 0, 0, 0);
                }
            }
        }
    }

    // epilogue: D layout col = lane&15, row = (lane>>4)*4 + reg
    #pragma unroll
    for (int mf = 0; mf < 4; ++mf) {
        const long row0 = i0 + wr + mf*16 + G*4;
        #pragma unroll
        for (int nf = 0; nf < 4; ++nf) {
            const long col = j0 + wc + nf*16 + rr;
            float bsum = 0.f;
            if (bias1) bsum += bias1[col];
            if (bias2) bsum += bias2[col];
            #pragma unroll
            for (int r = 0; r < 4; ++r) {
                const long row = row0 + r;
                float v = acc[mf][nf][r] * cscale + bsum;
                if (addend) v += addend[row*ldc + col];
                C[row*ldc + col] = v;
            }
        }
    }
}

// ---------------------------------------------------------------------------
// Split-K GEMM: Cpart[z][i,j] = sum_{k in chunk z} A[i,k]*B[k,j]  (fp32)
// ---------------------------------------------------------------------------
__global__ __launch_bounds__(256)
void gemm_ab128_splitk(const float* __restrict__ A, const float* __restrict__ B,
                       float* __restrict__ Cpart, int kchunk)
{
    __shared__ __align__(16) float As[8][132];
    __shared__ __align__(16) float Bs[8][132];
    const int tid = threadIdx.x;
    const int tx = tid & 15;
    const int ty = tid >> 4;
    const long i0 = (long)blockIdx.y * 128;
    const long j0 = (long)blockIdx.x * 128;
    const int kbase = blockIdx.z * kchunk;
    const int lr = tid >> 1;
    const int lk = (tid & 1) * 4;
    const int bkr = tid >> 5;
    const int bc  = (tid & 31) * 4;

    float acc[2][2][4][4] = {};

    for (int k0 = kbase; k0 < kbase + kchunk; k0 += 8) {
        float4 av = *(const float4*)&A[(i0 + lr) * 65536L + k0 + lk];
        float4 bv = *(const float4*)&B[(long)(k0 + bkr) * 512 + j0 + bc];
        __syncthreads();
        As[lk+0][lr] = av.x; As[lk+1][lr] = av.y; As[lk+2][lr] = av.z; As[lk+3][lr] = av.w;
        *(float4*)&Bs[bkr][bc] = bv;
        __syncthreads();
        #pragma unroll
        for (int kk = 0; kk < 8; ++kk) {
            float4 a0 = *(const float4*)&As[kk][ty*4];
            float4 a1 = *(const float4*)&As[kk][64 + ty*4];
            float4 b0 = *(const float4*)&Bs[kk][tx*4];
            float4 b1 = *(const float4*)&Bs[kk][64 + tx*4];
            fma44(acc[0][0], a0, b0); fma44(acc[0][1], a0, b1);
            fma44(acc[1][0], a1, b0); fma44(acc[1][1], a1, b1);
        }
    }

    float* Cp = Cpart + (size_t)blockIdx.z * (512*512);
    #pragma unroll
    for (int qi = 0; qi < 2; ++qi) {
        #pragma unroll
        for (int rr = 0; rr < 4; ++rr) {
            const long r = i0 + qi*64 + ty*4 + rr;
            #pragma unroll
            for (int qj = 0; qj < 2; ++qj) {
                const long c = j0 + qj*64 + tx*4;
                float4 v;
                v.x = acc[qi][qj][rr][0]; v.y = acc[qi][qj][rr][1];
                v.z = acc[qi][qj][rr][2]; v.w = acc[qi][qj][rr][3];
                *(float4*)&Cp[r*512 + c] = v;
            }
        }
    }
}

__global__ __launch_bounds__(256)
void reduce_parts16(const float* __restrict__ part, float* __restrict__ outp)
{
    const size_t idx = ((size_t)blockIdx.x * 256 + threadIdx.x) * 4;
    float4 s = *(const float4*)&part[idx];
    #pragma unroll
    for (int p = 1; p < 16; ++p) {
        float4 v = *(const float4*)&part[(size_t)p * 262144 + idx];
        s.x += v.x; s.y += v.y; s.z += v.z; s.w += v.w;
    }
    *(float4*)&outp[idx] = s;
}

// ---------------------------------------------------------------------------
// In-place row softmax over 65536 columns; one block per row.
// ---------------------------------------------------------------------------
__global__ __launch_bounds__(256)
void softmax_rows(float* __restrict__ L)
{
    __shared__ float red[4];
    const long base = (long)blockIdx.x * 65536;
    const int tid = threadIdx.x;

    float mx = -3.0e38f;
    for (int i = tid*4; i < 65536; i += 1024) {
        float4 v = *(const float4*)&L[base + i];
        mx = fmaxf(mx, fmaxf(fmaxf(v.x, v.y), fmaxf(v.z, v.w)));
    }
    #pragma unroll
    for (int off = 32; off > 0; off >>= 1) mx = fmaxf(mx, __shfl_xor(mx, off, 64));
    if ((tid & 63) == 0) red[tid >> 6] = mx;
    __syncthreads();
    mx = fmaxf(fmaxf(red[0], red[1]), fmaxf(red[2], red[3]));
    __syncthreads();

    float s = 0.f;
    for (int i = tid*4; i < 65536; i += 1024) {
        float4 v = *(const float4*)&L[base + i];
        v.x = __expf(v.x - mx); v.y = __expf(v.y - mx);
        v.z = __expf(v.z - mx); v.w = __expf(v.w - mx);
        *(float4*)&L[base + i] = v;
        s += v.x + v.y + v.z + v.w;
    }
    #pragma unroll
    for (int off = 32; off > 0; off >>= 1) s += __shfl_xor(s, off, 64);
    if ((tid & 63) == 0) red[tid >> 6] = s;
    __syncthreads();
    s = red[0] + red[1] + red[2] + red[3];
    const float inv = 1.f / s;

    for (int i = tid*4; i < 65536; i += 1024) {
        float4 v = *(const float4*)&L[base + i];
        v.x *= inv; v.y *= inv; v.z *= inv; v.w *= inv;
        *(float4*)&L[base + i] = v;
    }
}

// ---------------------------------------------------------------------------
// In-place row softmax over 512 cols; one wave per row, 4 rows/block.
// ---------------------------------------------------------------------------
__global__ __launch_bounds__(256)
void softmax512(float* __restrict__ S)
{
    const int wv = threadIdx.x >> 6, lnn = threadIdx.x & 63;
    const long row = (long)blockIdx.x * 4 + wv;
    float* p = S + row * 512 + lnn * 8;
    float4 v0 = *(float4*)p;
    float4 v1 = *(float4*)(p + 4);
    float mx = fmaxf(fmaxf(fmaxf(v0.x, v0.y), fmaxf(v0.z, v0.w)),
                     fmaxf(fmaxf(v1.x, v1.y), fmaxf(v1.z, v1.w)));
    #pragma unroll
    for (int off = 32; off > 0; off >>= 1) mx = fmaxf(mx, __shfl_xor(mx, off, 64));
    v0.x = __expf(v0.x - mx); v0.y = __expf(v0.y - mx);
    v0.z = __expf(v0.z - mx); v0.w = __expf(v0.w - mx);
    v1.x = __expf(v1.x - mx); v1.y = __expf(v1.y - mx);
    v1.z = __expf(v1.z - mx); v1.w = __expf(v1.w - mx);
    float s = v0.x + v0.y + v0.z + v0.w + v1.x + v1.y + v1.z + v1.w;
    #pragma unroll
    for (int off = 32; off > 0; off >>= 1) s += __shfl_xor(s, off, 64);
    const float inv = 1.f / s;
    v0.x *= inv; v0.y *= inv; v0.z *= inv; v0.w *= inv;
    v1.x *= inv; v1.y *= inv; v1.z *= inv; v1.w *= inv;
    *(float4*)p = v0;
    *(float4*)(p + 4) = v1;
}

// ---------------------------------------------------------------------------
// In-place LayerNorm over 512 cols; one wave per row, 4 rows/block.
// ---------------------------------------------------------------------------
__global__ __launch_bounds__(256)
void layernorm512(float* __restrict__ io, const float* __restrict__ gamma,
                  const float* __restrict__ beta)
{
    const int wv = threadIdx.x >> 6, lnn = threadIdx.x & 63;
    const long row = (long)blockIdx.x * 4 + wv;
    float* p = io + row * 512 + lnn * 8;
    float4 v0 = *(float4*)p;
    float4 v1 = *(float4*)(p + 4);
    float s = v0.x + v0.y + v0.z + v0.w + v1.x + v1.y + v1.z + v1.w;
    #pragma unroll
    for (int off = 32; off > 0; off >>= 1) s += __shfl_xor(s, off, 64);
    const float mu = s * (1.f/512.f);
    float qs = 0.f;
    {
        float d;
        d = v0.x-mu; qs += d*d; d = v0.y-mu; qs += d*d;
        d = v0.z-mu; qs += d*d; d = v0.w-mu; qs += d*d;
        d = v1.x-mu; qs += d*d; d = v1.y-mu; qs += d*d;
        d = v1.z-mu; qs += d*d; d = v1.w-mu; qs += d*d;
    }
    #pragma unroll
    for (int off = 32; off > 0; off >>= 1) qs += __shfl_xor(qs, off, 64);
    const float rstd = rsqrtf(qs * (1.f/512.f) + LN_EPS);
    float4 g0 = *(const float4*)(gamma + lnn*8);
    float4 g1 = *(const float4*)(gamma + lnn*8 + 4);
    float4 b0 = *(const float4*)(beta + lnn*8);
    float4 b1 = *(const float4*)(beta + lnn*8 + 4);
    v0.x = (v0.x-mu)*rstd*g0.x + b0.x; v0.y = (v0.y-mu)*rstd*g0.y + b0.y;
    v0.z = (v0.z-mu)*rstd*g0.z + b0.z; v0.w = (v0.w-mu)*rstd*g0.w + b0.w;
    v1.x = (v1.x-mu)*rstd*g1.x + b1.x; v1.y = (v1.y-mu)*rstd*g1.y + b1.y;
    v1.z = (v1.z-mu)*rstd*g1.z + b1.z; v1.w = (v1.w-mu)*rstd*g1.w + b1.w;
    *(float4*)p = v0;
    *(float4*)(p + 4) = v1;
}

// ---------------------------------------------------------------------------
// outp[d][m] = in[m][d] * scale   (512x512 transpose)
// ---------------------------------------------------------------------------
__global__ __launch_bounds__(256)
void transpose_scale512(const float* __restrict__ in, float* __restrict__ outp,
                        float scale)
{
    __shared__ float t[32][33];
    const int lx = threadIdx.x & 31;
    const int ly = threadIdx.x >> 5;
    const int m0 = blockIdx.y * 32;
    const int d0 = blockIdx.x * 32;
    #pragma unroll
    for (int i = 0; i < 32; i += 8)
        t[ly + i][lx] = in[(long)(m0 + ly + i) * 512 + d0 + lx] * scale;
    __syncthreads();
    #pragma unroll
    for (int i = 0; i < 32; i += 8)
        outp[(long)(d0 + ly + i) * 512 + m0 + lx] = t[lx][ly + i];
}

// ---------------------------------------------------------------------------
extern "C" void kernel_launch(void* const* d_in, const int* in_sizes, int n_in,
                              void* d_out, int out_size, void* d_ws, size_t ws_size,
                              hipStream_t stream)
{
    (void)in_sizes; (void)n_in; (void)out_size; (void)ws_size;
    const float* g    = (const float*)d_in[0];
    const float* g_p  = (const float*)d_in[1];
    const float* W    = (const float*)d_in[2];   // [1, 512, 512] == Ws
    const float* Wq   = (const float*)d_in[3];
    const float* bq   = (const float*)d_in[4];
    const float* Wk   = (const float*)d_in[5];
    const float* bk   = (const float*)d_in[6];
    const float* Wv   = (const float*)d_in[7];
    const float* bv   = (const float*)d_in[8];
    const float* Wgp  = (const float*)d_in[9];
    const float* bgp  = (const float*)d_in[10];
    const float* Wkp  = (const float*)d_in[11];
    const float* bkp  = (const float*)d_in[12];
    const float* gamma= (const float*)d_in[13];
    const float* beta = (const float*)d_in[14];
    float* out = (float*)d_out;

    // workspace (20 MB, same footprint as previous session):
    //   part  [16 MB]  split-K partials; later reused as S-band [8192 x 512]
    //   kp0   [1 MB]   pool @ g_p; later reused as Vt (V transposed)
    //   kp    [1 MB]
    //   Kmat  [1 MB]
    //   Vmat  [1 MB]
    float* w    = (float*)d_ws;
    float* part = w;
    float* kp0  = w + (size_t)16*262144;
    float* kp   = kp0 + 262144;
    float* Kmat = kp  + 262144;
    float* Vmat = Kmat + 262144;
    float* Sband = part;   // 8192x512 fp32 = 16 MB
    float* Vt    = kp0;    // kp0 dead after kp computed

    // 1) L = Ws @ g^T  -> d_out viewed as [512, 65536]   (MFMA hi/lo)
    mfma_bt<<<dim3(512, 4), 256, 0, stream>>>(
        W, g, nullptr, nullptr, nullptr, nullptr, nullptr,
        out, 512, 512, 512, (long)65536, 1.f);

    // 2) pool = softmax(L) rows, in place
    softmax_rows<<<dim3(512), 256, 0, stream>>>(out);

    // 3) k_p0 = pool @ g_p  (split-K 16, fp32)
    gemm_ab128_splitk<<<dim3(4, 4, 16), 256, 0, stream>>>(out, g_p, part, 4096);
    reduce_parts16<<<dim3(256), 256, 0, stream>>>(part, kp0);

    // 4) small fp32 GEMMs: k_p, K, V
    gemm_bt128<<<dim3(4, 4), 256, 0, stream>>>(
        kp0, Wkp, nullptr, nullptr, bkp, nullptr, nullptr, kp, 512, 512, 512, (long)512, 1.f);
    gemm_bt128<<<dim3(4, 4), 256, 0, stream>>>(
        W, Wk, nullptr, nullptr, bk, nullptr, kp, Kmat, 512, 512, 512, (long)512, 1.f);
    gemm_bt128<<<dim3(4, 4), 256, 0, stream>>>(
        W, Wv, nullptr, nullptr, bv, nullptr, nullptr, Vmat, 512, 512, 512, (long)512, 1.f);

    // 4b) Vt = Vmat^T (kp0 slot is dead now)
    transpose_scale512<<<dim3(16, 16), 256, 0, stream>>>(Vmat, Vt, 1.f);

    // 5) Q = g @ Wq^T + g_p @ Wgp^T + bq + bgp  -> d_out as [65536, 512]  (MFMA)
    mfma_bt<<<dim3(4, 512), 256, 0, stream>>>(
        g, Wq, g_p, Wgp, bq, bgp, nullptr, out, 512, 512, 512, (long)512, 1.f);

    // 6) attention in 8 row-bands of 8192 (Q band in d_out is dead once its
    //    scores are computed, so PV may overwrite the band in place)
    for (int b = 0; b < 8; ++b) {
        const size_t off = (size_t)b * 8192 * 512;
        // S = Q_band @ K^T * SCALE  -> Sband
        mfma_bt<<<dim3(4, 64), 256, 0, stream>>>(
            out + off, Kmat, nullptr, nullptr, nullptr, nullptr, nullptr,
            Sband, 512, 512, 512, (long)512, SCALE_ATT);
        // P = softmax rows
        softmax512<<<dim3(2048), 256, 0, stream>>>(Sband);
        // O = P @ Vt^T + g_band  -> out band (in place)
        mfma_bt<<<dim3(4, 64), 256, 0, stream>>>(
            Sband, Vt, nullptr, nullptr, nullptr, nullptr, g + off,
            out + off, 512, 512, 512, (long)512, 1.f);
    }

    // 7) LayerNorm in place over [65536, 512]
    layernorm512<<<dim3(16384), 256, 0, stream>>>(out, gamma, beta);
}